// Round 6
// baseline (363.932 us; speedup 1.0000x reference)
//
#include <hip/hip_runtime.h>
#include <hip/hip_bf16.h>
#include <math.h>

#define S_ 16384
#define D_ 2048
#define DM_ 64
#define DK_ 384
#define NMEM_ 128
#define EPS_ 1e-5f

typedef __attribute__((ext_vector_type(8))) short bf16x8;
typedef __attribute__((ext_vector_type(8))) short s16x8;
typedef __attribute__((ext_vector_type(4))) float f32x4;
typedef unsigned short u16;

static __device__ __forceinline__ u16 f2bf(float x) {
    __hip_bfloat16 h = __float2bfloat16(x);
    return *reinterpret_cast<u16*>(&h);
}

static __device__ __forceinline__ float bf2f(u16 u) {
    unsigned int x = ((unsigned int)u) << 16;
    union { unsigned int i; float f; } c; c.i = x;
    return c.f;
}

static __device__ __forceinline__ bf16x8 cvt8(float4 a0, float4 a1) {
    bf16x8 r;
    r[0] = (short)f2bf(a0.x); r[1] = (short)f2bf(a0.y);
    r[2] = (short)f2bf(a0.z); r[3] = (short)f2bf(a0.w);
    r[4] = (short)f2bf(a1.x); r[5] = (short)f2bf(a1.y);
    r[6] = (short)f2bf(a1.z); r[7] = (short)f2bf(a1.w);
    return r;
}

static __device__ __forceinline__ void gload16(const void* g, void* l) {
    __builtin_amdgcn_global_load_lds(
        (const __attribute__((address_space(1))) unsigned int*)g,
        (__attribute__((address_space(3))) unsigned int*)l, 16, 0, 0);
}

// ---------------- k_qprep: Wmv cvt [0,4096) | WmT transpose [4096,4864) |
//                  LDS-free fused Q-GEMM+dpfp+denom [4864,5120)
__global__ __launch_bounds__(256) void k_qprep(const float* __restrict__ hs,
                                               const float* __restrict__ Wmq,
                                               const float* __restrict__ Wmv,
                                               const float* __restrict__ Wmem,
                                               const float* __restrict__ z,
                                               u16* __restrict__ Wmv_b,
                                               u16* __restrict__ WmT,
                                               u16* __restrict__ mq_b,
                                               float* __restrict__ denomv) {
    __shared__ float ts[32][33];
    __shared__ u16 xs[4][16][136];    // padded: row stride 136 u16 spreads banks
    __shared__ float zs[DK_];
    const int bid = blockIdx.x;
    const int tid = threadIdx.x;
    if (bid < 4096) {
        size_t idx = ((size_t)bid * 256 + tid) * 4;
        float4 v = *reinterpret_cast<const float4*>(&Wmv[idx]);
        ushort4 p;
        p.x = f2bf(v.x); p.y = f2bf(v.y); p.z = f2bf(v.z); p.w = f2bf(v.w);
        *reinterpret_cast<ushort4*>(&Wmv_b[idx]) = p;
        return;
    }
    if (bid < 4864) {
        int t = bid - 4096;
        int c0 = (t & 63) * 32, k0 = (t >> 6) * 32;
        const int tx = tid & 31, ty = tid >> 5;
#pragma unroll
        for (int i = 0; i < 4; ++i)
            ts[ty + 8 * i][tx] = Wmem[(size_t)(k0 + ty + 8 * i) * D_ + c0 + tx];
        __syncthreads();
#pragma unroll
        for (int i = 0; i < 4; ++i)
            WmT[(size_t)(c0 + ty + 8 * i) * DK_ + k0 + tx] = f2bf(ts[tx][ty + 8 * i]);
        return;
    }
    // ------- qdp: wave-private direct-register GEMM, no LDS in K-loop
    const int qb = bid - 4864;          // 0..255
    const int lane = tid & 63, w = tid >> 6;
    const int lrow = lane & 15, lkg = lane >> 4;
    const int r0w = qb * 64 + w * 16;   // wave's 16 rows
    for (int i = tid; i < DK_; i += 256) zs[i] = z[i];
    const float* __restrict__ ap  = hs + (size_t)(r0w + lrow) * D_ + lkg * 8;
    const float* __restrict__ bp0 = Wmq + (size_t)lrow * D_ + lkg * 8;
    const float* __restrict__ bp1 = bp0 + (size_t)16 * D_;
    const float* __restrict__ bp2 = bp0 + (size_t)32 * D_;
    const float* __restrict__ bp3 = bp0 + (size_t)48 * D_;
    f32x4 acc[4];
    const f32x4 zero4 = {0.f, 0.f, 0.f, 0.f};
#pragma unroll
    for (int n = 0; n < 4; ++n) acc[n] = zero4;
#pragma unroll 4
    for (int kk = 0; kk < 64; ++kk) {
        const int k0 = kk * 32;
        float4 a0 = *reinterpret_cast<const float4*>(ap + k0);
        float4 a1 = *reinterpret_cast<const float4*>(ap + k0 + 4);
        float4 b00 = *reinterpret_cast<const float4*>(bp0 + k0);
        float4 b01 = *reinterpret_cast<const float4*>(bp0 + k0 + 4);
        float4 b10 = *reinterpret_cast<const float4*>(bp1 + k0);
        float4 b11 = *reinterpret_cast<const float4*>(bp1 + k0 + 4);
        float4 b20 = *reinterpret_cast<const float4*>(bp2 + k0);
        float4 b21 = *reinterpret_cast<const float4*>(bp2 + k0 + 4);
        float4 b30 = *reinterpret_cast<const float4*>(bp3 + k0);
        float4 b31 = *reinterpret_cast<const float4*>(bp3 + k0 + 4);
        bf16x8 af = cvt8(a0, a1);
        acc[0] = __builtin_amdgcn_mfma_f32_16x16x32_bf16(af, cvt8(b00, b01), acc[0], 0, 0, 0);
        acc[1] = __builtin_amdgcn_mfma_f32_16x16x32_bf16(af, cvt8(b10, b11), acc[1], 0, 0, 0);
        acc[2] = __builtin_amdgcn_mfma_f32_16x16x32_bf16(af, cvt8(b20, b21), acc[2], 0, 0, 0);
        acc[3] = __builtin_amdgcn_mfma_f32_16x16x32_bf16(af, cvt8(b30, b31), acc[3], 0, 0, 0);
    }
    // Q frags -> xs (bf16): x = [relu(q), relu(-q)]
#pragma unroll
    for (int n = 0; n < 4; ++n) {
        int col = n * 16 + lrow;
#pragma unroll
        for (int r = 0; r < 4; ++r) {
            int row = lkg * 4 + r;
            float q = acc[n][r];
            xs[w][row][col] = f2bf(fmaxf(q, 0.f));
            xs[w][row][col + 64] = f2bf(fmaxf(-q, 0.f));
        }
    }
    __syncthreads();
    // dpfp: 4 threads per row (64 rows), 96 m-values each, 16B stores
    {
        int row = tid >> 2, sub = tid & 3;
        int wv = row >> 4, rr = row & 15;
        float pd = 0.f;
#pragma unroll
        for (int c = 0; c < 12; ++c) {
            int base = sub * 96 + c * 8;
            int g = base >> 7;          // chunks are 8-aligned: g constant in chunk
            s16x8 pk;
#pragma unroll
            for (int e = 0; e < 8; ++e) {
                int m = base + e;
                int i = m & 127;
                float xi = bf2f(xs[wv][rr][i]);
                float xj = bf2f(xs[wv][rr][(i - g - 1) & 127]);
                float v = xi * xj;
                pd += zs[m] * v;
                pk[e] = (short)f2bf(v);
            }
            *reinterpret_cast<s16x8*>(&mq_b[(size_t)(qb * 64 + row) * DK_ + base]) = pk;
        }
        pd += __shfl_down(pd, 2, 4);
        pd += __shfl_down(pd, 1, 4);
        if (sub == 0) denomv[qb * 64 + row] = pd + EPS_;
    }
}

// ---------------- k_main: out = (mq @ WmT^T)/denom + hs, BK=64 (m97 structure)
__global__ __launch_bounds__(256) void k_main(const float* __restrict__ hs,
                                              const u16* __restrict__ mq_b,
                                              const u16* __restrict__ WmT,
                                              const float* __restrict__ denomv,
                                              float* __restrict__ out) {
    __shared__ u16 At[128 * 64];
    __shared__ u16 Bt[128 * 64];
    __shared__ float dinv[128];
    const int bid = blockIdx.x;
    const int swz = (bid & 7) * 256 + (bid >> 3);   // XCD chunked, 2048 % 8 == 0
    const int r0 = (swz >> 4) * 128, c0 = (swz & 15) * 128;
    const int tid = threadIdx.x;
    const int lane = tid & 63, w = tid >> 6;
    const int lrow = lane & 15, lkg = lane >> 4;
    const int wr = w >> 1, wc = w & 1;
    if (tid < 128) dinv[tid] = 1.f / denomv[r0 + tid];
    f32x4 acc[4][4];
    const f32x4 zero4 = {0.f, 0.f, 0.f, 0.f};
#pragma unroll
    for (int m = 0; m < 4; ++m)
#pragma unroll
        for (int n = 0; n < 4; ++n) acc[m][n] = zero4;
    for (int kc = 0; kc < 6; ++kc) {
#pragma unroll
        for (int i = 0; i < 4; ++i) {
            int rr = w * 32 + i * 8 + (lane >> 3);
            int gg = (lane & 7) ^ (rr & 7);
            gload16(mq_b + (size_t)(r0 + rr) * DK_ + kc * 64 + gg * 8,
                    &At[(w * 32 + i * 8) * 64]);
            gload16(WmT + (size_t)(c0 + rr) * DK_ + kc * 64 + gg * 8,
                    &Bt[(w * 32 + i * 8) * 64]);
        }
        __syncthreads();
#pragma unroll
        for (int s = 0; s < 2; ++s) {
            bf16x8 af[4], bb[4];
#pragma unroll
            for (int m = 0; m < 4; ++m) {
                int rl = wr * 64 + m * 16 + lrow;
                af[m] = *reinterpret_cast<const bf16x8*>(
                    &At[rl * 64 + (((s * 4 + lkg) ^ (rl & 7)) * 8)]);
            }
#pragma unroll
            for (int n = 0; n < 4; ++n) {
                int cl = wc * 64 + n * 16 + lrow;
                bb[n] = *reinterpret_cast<const bf16x8*>(
                    &Bt[cl * 64 + (((s * 4 + lkg) ^ (cl & 7)) * 8)]);
            }
#pragma unroll
            for (int m = 0; m < 4; ++m)
#pragma unroll
                for (int n = 0; n < 4; ++n)
                    acc[m][n] = __builtin_amdgcn_mfma_f32_16x16x32_bf16(
                        af[m], bb[n], acc[m][n], 0, 0, 0);
        }
        __syncthreads();
    }
#pragma unroll
    for (int m = 0; m < 4; ++m)
#pragma unroll
        for (int n = 0; n < 4; ++n) {
            int colg = c0 + wc * 64 + n * 16 + lrow;
#pragma unroll
            for (int r = 0; r < 4; ++r) {
                int rowl = wr * 64 + m * 16 + lkg * 4 + r;
                size_t off = (size_t)(r0 + rowl) * D_ + colg;
                out[off] = acc[m][n][r] * dinv[rowl] + hs[off];
            }
        }
}

// ---------------- k_mk: per mem-token row: mk, denom2, nic, mb; also mem_b bf16
__global__ __launch_bounds__(256) void k_mk(const float* __restrict__ out,
                                            const float* __restrict__ Wmk,
                                            const float* __restrict__ Wmb_w,
                                            const float* __restrict__ Wmb_b,
                                            const float* __restrict__ z,
                                            float* __restrict__ mk_g,
                                            u16* __restrict__ mk_b,
                                            u16* __restrict__ mem_b,
                                            float* __restrict__ scal) {
    __shared__ float memRow[D_];
    __shared__ float qpart[4][64];
    __shared__ float xv[128];
    __shared__ float mks[DK_];
    __shared__ float red[256];
    const int j = blockIdx.x;
    const int tid = threadIdx.x;
    const float* mem = out + (size_t)(S_ - NMEM_ + j) * D_;
    const float4* mem4 = reinterpret_cast<const float4*>(mem);
    float4* mr4 = reinterpret_cast<float4*>(memRow);
#pragma unroll
    for (int i4 = tid; i4 < 512; i4 += 256) {
        float4 v = mem4[i4];
        mr4[i4] = v;
        ushort4 p;
        p.x = f2bf(v.x); p.y = f2bf(v.y); p.z = f2bf(v.z); p.w = f2bf(v.w);
        *reinterpret_cast<ushort4*>(&mem_b[(size_t)j * D_ + i4 * 4]) = p;
    }
    __syncthreads();
    {
        int c = tid & 63, seg = tid >> 6;
        const float4* wrow = reinterpret_cast<const float4*>(Wmk + (size_t)c * D_);
        float p = 0.f;
#pragma unroll 4
        for (int k4 = seg * 128; k4 < seg * 128 + 128; ++k4) {
            float4 a = mr4[k4], b = wrow[k4];
            p += a.x * b.x + a.y * b.y + a.z * b.z + a.w * b.w;
        }
        qpart[seg][c] = p;
    }
    __syncthreads();
    if (tid < 64) {
        float q = qpart[0][tid] + qpart[1][tid] + qpart[2][tid] + qpart[3][tid];
        xv[tid] = fmaxf(q, 0.f);
        xv[tid + 64] = fmaxf(-q, 0.f);
    }
    __syncthreads();
    for (int m = tid; m < DK_; m += 256) {
        int i = m & 127, g = m >> 7;
        float v = xv[i] * xv[(i - g - 1) & 127];
        mks[m] = v;
        mk_g[(size_t)j * DK_ + m] = v;
        mk_b[(size_t)j * DK_ + m] = f2bf(v);
    }
    __syncthreads();
    float pd = 0.f, ps = 0.f;
    for (int m = tid; m < DK_; m += 256) { float v = mks[m]; pd += v * z[m]; ps += v * v; }
    red[tid] = pd; __syncthreads();
    for (int s = 128; s > 0; s >>= 1) { if (tid < s) red[tid] += red[tid + s]; __syncthreads(); }
    float denom2 = red[0] + EPS_;
    __syncthreads();
    red[tid] = ps; __syncthreads();
    for (int s = 128; s > 0; s >>= 1) { if (tid < s) red[tid] += red[tid + s]; __syncthreads(); }
    float mksq = red[0];
    __syncthreads();
    float pb = 0.f;
    {
        const float4* wb4 = reinterpret_cast<const float4*>(Wmb_w);
#pragma unroll
        for (int k4 = tid; k4 < 512; k4 += 256) {
            float4 a = mr4[k4], b = wb4[k4];
            pb += a.x * b.x + a.y * b.y + a.z * b.z + a.w * b.w;
        }
    }
    red[tid] = pb; __syncthreads();
    for (int s = 128; s > 0; s >>= 1) { if (tid < s) red[tid] += red[tid + s]; __syncthreads(); }
    if (tid == 0) {
        float bsum = red[0] + Wmb_b[0];
        float mb = 1.f / (1.f + expf(-bsum));
        float nic = 1.f - denom2 / (mksq + EPS_);
        nic = fminf(fmaxf(nic, 0.f), 1.f);
        scal[j * 4 + 0] = denom2;
        scal[j * 4 + 1] = nic;
        scal[j * 4 + 2] = mb;
        scal[j * 4 + 3] = mksq;
    }
}

// ---------------- k_mv (MFMA): mvb = (mem@Wmv^T - (mk@W_mem)/denom2)*mb
// BM=128, BN=64 -> grid 32
__global__ __launch_bounds__(256) void k_mv(const u16* __restrict__ mem_b,
                                            const u16* __restrict__ Wmv_b,
                                            const u16* __restrict__ mk_b,
                                            const u16* __restrict__ WmT,
                                            const float* __restrict__ scal,
                                            float* __restrict__ mvb) {
    __shared__ u16 At[128 * 64];
    __shared__ u16 Bt[64 * 64];
    __shared__ float inv2[128];
    __shared__ float mbl[128];
    const int c0 = blockIdx.x * 64;
    const int tid = threadIdx.x;
    const int lane = tid & 63, w = tid >> 6;
    const int lrow = lane & 15, lkg = lane >> 4;
    const int wr = w >> 1, wc = w & 1;
    if (tid < 128) {
        inv2[tid] = 1.f / scal[tid * 4 + 0];
        mbl[tid] = scal[tid * 4 + 2];
    }
    f32x4 acc1[4][2], acc2[4][2];
    const f32x4 zero4 = {0.f, 0.f, 0.f, 0.f};
#pragma unroll
    for (int m = 0; m < 4; ++m)
#pragma unroll
        for (int n = 0; n < 2; ++n) { acc1[m][n] = zero4; acc2[m][n] = zero4; }
    for (int kc = 0; kc < D_ / 64; ++kc) {
#pragma unroll
        for (int i = 0; i < 4; ++i) {
            int rr = w * 32 + i * 8 + (lane >> 3);
            int gg = (lane & 7) ^ (rr & 7);
            gload16(mem_b + (size_t)rr * D_ + kc * 64 + gg * 8,
                    &At[(w * 32 + i * 8) * 64]);
        }
#pragma unroll
        for (int i = 0; i < 2; ++i) {
            int cc = w * 16 + i * 8 + (lane >> 3);
            int gg = (lane & 7) ^ (cc & 7);
            gload16(Wmv_b + (size_t)(c0 + cc) * D_ + kc * 64 + gg * 8,
                    &Bt[(w * 16 + i * 8) * 64]);
        }
        __syncthreads();
#pragma unroll
        for (int s = 0; s < 2; ++s) {
            bf16x8 af[4], bb[2];
#pragma unroll
            for (int m = 0; m < 4; ++m) {
                int rl = wr * 64 + m * 16 + lrow;
                af[m] = *reinterpret_cast<const bf16x8*>(
                    &At[rl * 64 + (((s * 4 + lkg) ^ (rl & 7)) * 8)]);
            }
#pragma unroll
            for (int n = 0; n < 2; ++n) {
                int cl = wc * 32 + n * 16 + lrow;
                bb[n] = *reinterpret_cast<const bf16x8*>(
                    &Bt[cl * 64 + (((s * 4 + lkg) ^ (cl & 7)) * 8)]);
            }
#pragma unroll
            for (int m = 0; m < 4; ++m)
#pragma unroll
                for (int n = 0; n < 2; ++n)
                    acc1[m][n] = __builtin_amdgcn_mfma_f32_16x16x32_bf16(
                        af[m], bb[n], acc1[m][n], 0, 0, 0);
        }
        __syncthreads();
    }
    for (int kc = 0; kc < 6; ++kc) {
#pragma unroll
        for (int i = 0; i < 4; ++i) {
            int rr = w * 32 + i * 8 + (lane >> 3);
            int gg = (lane & 7) ^ (rr & 7);
            gload16(mk_b + (size_t)rr * DK_ + kc * 64 + gg * 8,
                    &At[(w * 32 + i * 8) * 64]);
        }
#pragma unroll
        for (int i = 0; i < 2; ++i) {
            int cc = w * 16 + i * 8 + (lane >> 3);
            int gg = (lane & 7) ^ (cc & 7);
            gload16(WmT + (size_t)(c0 + cc) * DK_ + kc * 64 + gg * 8,
                    &Bt[(w * 16 + i * 8) * 64]);
        }
        __syncthreads();
#pragma unroll
        for (int s = 0; s < 2; ++s) {
            bf16x8 af[4], bb[2];
#pragma unroll
            for (int m = 0; m < 4; ++m) {
                int rl = wr * 64 + m * 16 + lrow;
                af[m] = *reinterpret_cast<const bf16x8*>(
                    &At[rl * 64 + (((s * 4 + lkg) ^ (rl & 7)) * 8)]);
            }
#pragma unroll
            for (int n = 0; n < 2; ++n) {
                int cl = wc * 32 + n * 16 + lrow;
                bb[n] = *reinterpret_cast<const bf16x8*>(
                    &Bt[cl * 64 + (((s * 4 + lkg) ^ (cl & 7)) * 8)]);
            }
#pragma unroll
            for (int m = 0; m < 4; ++m)
#pragma unroll
                for (int n = 0; n < 2; ++n)
                    acc2[m][n] = __builtin_amdgcn_mfma_f32_16x16x32_bf16(
                        af[m], bb[n], acc2[m][n], 0, 0, 0);
        }
        __syncthreads();
    }
#pragma unroll
    for (int m = 0; m < 4; ++m)
#pragma unroll
        for (int n = 0; n < 2; ++n) {
            int colg = c0 + wc * 32 + n * 16 + lrow;
#pragma unroll
            for (int r = 0; r < 4; ++r) {
                int j = wr * 64 + m * 16 + lkg * 4 + r;
                mvb[(size_t)j * D_ + colg] =
                    (acc1[m][n][r] - acc2[m][n][r] * inv2[j]) * mbl[j];
            }
        }
}

// ---------------- k_wmem: W_mem_new = W_mem + mk^T @ mvb (float4) ; y==48 z_new
__global__ __launch_bounds__(256) void k_wmem(const float* __restrict__ Wmem,
                                              const float* __restrict__ mk_g,
                                              const float* __restrict__ mvb,
                                              const float* __restrict__ scal,
                                              const float* __restrict__ z,
                                              float* __restrict__ wout,
                                              float* __restrict__ zout) {
    const int tid = threadIdx.x;
    if (blockIdx.y == 48) {
        if (blockIdx.x == 0) {
            for (int t = tid; t < DK_; t += 256) {
                float acc = z[t];
                for (int j = 0; j < NMEM_; ++j)
                    acc += scal[j * 4 + 1] * mk_g[(size_t)j * DK_ + t];
                zout[t] = acc;
            }
        }
        return;
    }
    const int c0 = blockIdx.x * 256;
    const int k0 = blockIdx.y * 8;
    const int tk = tid >> 5, tt = tid & 31;
    const float4* mvb4 = reinterpret_cast<const float4*>(mvb);
    f32x4 acc[2] = {{0.f, 0.f, 0.f, 0.f}, {0.f, 0.f, 0.f, 0.f}};
#pragma unroll 4
    for (int j = 0; j < NMEM_; ++j) {
        float a = mk_g[(size_t)j * DK_ + k0 + tk];
#pragma unroll
        for (int i = 0; i < 2; ++i) {
            float4 v = mvb4[((size_t)j * D_ + c0 + tt * 4 + 128 * i) >> 2];
            acc[i][0] += a * v.x; acc[i][1] += a * v.y;
            acc[i][2] += a * v.z; acc[i][3] += a * v.w;
        }
    }
#pragma unroll
    for (int i = 0; i < 2; ++i) {
        size_t off = (size_t)(k0 + tk) * D_ + c0 + tt * 4 + 128 * i;
        float4 wv = *reinterpret_cast<const float4*>(&Wmem[off]);
        float4 o;
        o.x = wv.x + acc[i][0]; o.y = wv.y + acc[i][1];
        o.z = wv.z + acc[i][2]; o.w = wv.w + acc[i][3];
        *reinterpret_cast<float4*>(&wout[off]) = o;
    }
}

extern "C" void kernel_launch(void* const* d_in, const int* in_sizes, int n_in,
                              void* d_out, int out_size, void* d_ws, size_t ws_size,
                              hipStream_t stream) {
    const float* hs   = (const float*)d_in[0];
    const float* Wmq  = (const float*)d_in[1];
    const float* Wmk  = (const float*)d_in[2];
    const float* Wmv  = (const float*)d_in[3];
    const float* Wmbw = (const float*)d_in[4];
    const float* Wmbb = (const float*)d_in[5];
    const float* Wmem = (const float*)d_in[6];
    const float* z    = (const float*)d_in[7];
    float* out  = (float*)d_out;
    float* wout = out + (size_t)S_ * D_;
    float* zout = wout + (size_t)DK_ * D_;

    float* ws = (float*)d_ws;
    float* denomv = ws;                              // 16384
    float* mk_g   = denomv + S_;                     // 128*384
    float* scal   = mk_g + (size_t)NMEM_ * DK_;      // 512
    float* mvb    = scal + NMEM_ * 4;                // 128*2048
    u16* mq_b  = (u16*)(mvb + (size_t)NMEM_ * D_);   // 16384*384 bf16
    u16* WmT   = mq_b + (size_t)S_ * DK_;            // 2048*384 bf16
    u16* Wmv_b = WmT + (size_t)D_ * DK_;             // 2048*2048 bf16
    u16* mem_b = Wmv_b + (size_t)D_ * D_;            // 128*2048 bf16
    u16* mk_b  = mem_b + (size_t)NMEM_ * D_;         // 128*384 bf16

    k_qprep<<<dim3(4864 + S_ / 64), 256, 0, stream>>>(hs, Wmq, Wmv, Wmem, z,
                                                      Wmv_b, WmT, mq_b, denomv);
    k_main<<<dim3((S_ / 128) * (D_ / 128)), 256, 0, stream>>>(hs, mq_b, WmT, denomv, out);
    k_mk<<<dim3(NMEM_), 256, 0, stream>>>(out, Wmk, Wmbw, Wmbb, z, mk_g, mk_b, mem_b, scal);
    k_mv<<<dim3(D_ / 64), 256, 0, stream>>>(mem_b, Wmv_b, mk_b, WmT, scal, mvb);
    k_wmem<<<dim3(D_ / 256, DK_ / 8 + 1), 256, 0, stream>>>(Wmem, mk_g, mvb, scal, z, wout, zout);
}

// Round 7
// 198.130 us; speedup vs baseline: 1.8368x; 1.8368x over previous
//
#include <hip/hip_runtime.h>
#include <hip/hip_bf16.h>
#include <math.h>

#define S_ 16384
#define D_ 2048
#define DM_ 64
#define DK_ 384
#define NMEM_ 128
#define EPS_ 1e-5f

typedef __attribute__((ext_vector_type(8))) short bf16x8;
typedef __attribute__((ext_vector_type(8))) short s16x8;
typedef __attribute__((ext_vector_type(4))) float f32x4;
typedef unsigned short u16;

static __device__ __forceinline__ u16 f2bf(float x) {
    __hip_bfloat16 h = __float2bfloat16(x);
    return *reinterpret_cast<u16*>(&h);
}

static __device__ __forceinline__ void gload16(const void* g, void* l) {
    __builtin_amdgcn_global_load_lds(
        (const __attribute__((address_space(1))) unsigned int*)g,
        (__attribute__((address_space(3))) unsigned int*)l, 16, 0, 0);
}

// ---------------- k_prep: all weight conversions in one launch
// [0,4096): Wmv f32->bf16 ; [4096,4224): Wmq ; [4224,4992): W_mem transpose
__global__ __launch_bounds__(256) void k_prep(const float* __restrict__ Wmq,
                                              const float* __restrict__ Wmv,
                                              const float* __restrict__ Wmem,
                                              u16* __restrict__ Wmq_b,
                                              u16* __restrict__ Wmv_b,
                                              u16* __restrict__ WmT) {
    __shared__ float ts[32][33];
    const int bid = blockIdx.x;
    const int tid = threadIdx.x;
    if (bid < 4096) {
        size_t idx = ((size_t)bid * 256 + tid) * 4;
        float4 v = *reinterpret_cast<const float4*>(&Wmv[idx]);
        ushort4 p;
        p.x = f2bf(v.x); p.y = f2bf(v.y); p.z = f2bf(v.z); p.w = f2bf(v.w);
        *reinterpret_cast<ushort4*>(&Wmv_b[idx]) = p;
    } else if (bid < 4224) {
        int idx = ((bid - 4096) * 256 + tid) * 4;
        float4 v = *reinterpret_cast<const float4*>(&Wmq[idx]);
        ushort4 p;
        p.x = f2bf(v.x); p.y = f2bf(v.y); p.z = f2bf(v.z); p.w = f2bf(v.w);
        *reinterpret_cast<ushort4*>(&Wmq_b[idx]) = p;
    } else {
        int t = bid - 4224;
        int c0 = (t & 63) * 32, k0 = (t >> 6) * 32;
        const int tx = tid & 31, ty = tid >> 5;
#pragma unroll
        for (int i = 0; i < 4; ++i)
            ts[ty + 8 * i][tx] = Wmem[(size_t)(k0 + ty + 8 * i) * D_ + c0 + tx];
        __syncthreads();
#pragma unroll
        for (int i = 0; i < 4; ++i)
            WmT[(size_t)(c0 + ty + 8 * i) * DK_ + k0 + tx] = f2bf(ts[tx][ty + 8 * i]);
    }
}

// ---------------- k_qdp: fused Q-GEMM + dpfp + denom
// BM=32, grid 512, 4 waves (2x2): wave = 16 rows x 32 cols, BK=64
__global__ __launch_bounds__(256) void k_qdp(const float* __restrict__ hs,
                                             const u16* __restrict__ Wmq_b,
                                             const float* __restrict__ z,
                                             u16* __restrict__ mq_b,
                                             float* __restrict__ denomv) {
    __shared__ u16 As[32 * 64];
    __shared__ u16 Bs[64 * 64];
    __shared__ float xs[32][128];
    __shared__ float zs[DK_];
    const int r0 = blockIdx.x * 32;
    const int tid = threadIdx.x;
    const int lane = tid & 63, w = tid >> 6;
    const int lrow = lane & 15, lkg = lane >> 4;
    const int wr = w >> 1, wc = w & 1;
    for (int i = tid; i < DK_; i += 256) zs[i] = z[i];
    f32x4 acc[2];
    const f32x4 zero4 = {0.f, 0.f, 0.f, 0.f};
    acc[0] = zero4; acc[1] = zero4;
    for (int kc = 0; kc < D_ / 64; ++kc) {
        // A: load f32, cvt, swizzled ds_write (slot g holds global granule g^(row&7))
#pragma unroll
        for (int i = 0; i < 2; ++i) {
            int flat4 = tid + 256 * i;
            int row = flat4 >> 4, c4 = flat4 & 15;
            const float4 v = *reinterpret_cast<const float4*>(
                &hs[(size_t)(r0 + row) * D_ + kc * 64 + c4 * 4]);
            int off = row * 64 + (((c4 >> 1) ^ (row & 7)) * 8) + (c4 & 1) * 4;
            ushort4 p;
            p.x = f2bf(v.x); p.y = f2bf(v.y); p.z = f2bf(v.z); p.w = f2bf(v.w);
            *reinterpret_cast<ushort4*>(&As[off]) = p;
        }
        // B: global_load_lds, pre-swizzled source, linear dest
#pragma unroll
        for (int i = 0; i < 2; ++i) {
            int col = w * 16 + i * 8 + (lane >> 3);
            int gg = (lane & 7) ^ (col & 7);
            gload16(Wmq_b + (size_t)col * D_ + kc * 64 + gg * 8,
                    &Bs[(w * 16 + i * 8) * 64]);
        }
        __syncthreads();
#pragma unroll
        for (int s = 0; s < 2; ++s) {
            int rl = wr * 16 + lrow;
            bf16x8 a_ = *reinterpret_cast<const bf16x8*>(
                &As[rl * 64 + (((s * 4 + lkg) ^ (rl & 7)) * 8)]);
#pragma unroll
            for (int n = 0; n < 2; ++n) {
                int cl = wc * 32 + n * 16 + lrow;
                bf16x8 b_ = *reinterpret_cast<const bf16x8*>(
                    &Bs[cl * 64 + (((s * 4 + lkg) ^ (cl & 7)) * 8)]);
                acc[n] = __builtin_amdgcn_mfma_f32_16x16x32_bf16(a_, b_, acc[n], 0, 0, 0);
            }
        }
        __syncthreads();
    }
    // Q fragments -> xs = [relu(q), relu(-q)]
#pragma unroll
    for (int n = 0; n < 2; ++n) {
        int col = wc * 32 + n * 16 + lrow;
#pragma unroll
        for (int r = 0; r < 4; ++r) {
            int row = wr * 16 + lkg * 4 + r;
            float q = acc[n][r];
            xs[row][col] = fmaxf(q, 0.f);
            xs[row][col + 64] = fmaxf(-q, 0.f);
        }
    }
    __syncthreads();
    // dpfp: 8 threads/row, 6 chunks of 8, vectorized 16B stores
    {
        int row = tid >> 3, sub = tid & 7;
        float pd = 0.f;
#pragma unroll
        for (int c = 0; c < 6; ++c) {
            int base = sub * 48 + c * 8;
            int g = base >> 7;          // 8-chunks never cross a 128 boundary
            s16x8 pk;
#pragma unroll
            for (int e = 0; e < 8; ++e) {
                int m = base + e;
                int i = m & 127;
                float v = xs[row][i] * xs[row][(i - g - 1) & 127];
                pd += zs[m] * v;
                pk[e] = (short)f2bf(v);
            }
            *reinterpret_cast<s16x8*>(&mq_b[(size_t)(r0 + row) * DK_ + base]) = pk;
        }
        pd += __shfl_down(pd, 4, 8);
        pd += __shfl_down(pd, 2, 8);
        pd += __shfl_down(pd, 1, 8);
        if (sub == 0) denomv[r0 + row] = pd + EPS_;
    }
}

// ---------------- k_main: out = (mq @ WmT^T)/denom + hs, BK=64 (m97 structure)
__global__ __launch_bounds__(256) void k_main(const float* __restrict__ hs,
                                              const u16* __restrict__ mq_b,
                                              const u16* __restrict__ WmT,
                                              const float* __restrict__ denomv,
                                              float* __restrict__ out) {
    __shared__ u16 At[128 * 64];
    __shared__ u16 Bt[128 * 64];
    __shared__ float dinv[128];
    const int bid = blockIdx.x;
    const int swz = (bid & 7) * 256 + (bid >> 3);   // XCD chunked, 2048 % 8 == 0
    const int r0 = (swz >> 4) * 128, c0 = (swz & 15) * 128;
    const int tid = threadIdx.x;
    const int lane = tid & 63, w = tid >> 6;
    const int lrow = lane & 15, lkg = lane >> 4;
    const int wr = w >> 1, wc = w & 1;
    if (tid < 128) dinv[tid] = 1.f / denomv[r0 + tid];
    f32x4 acc[4][4];
    const f32x4 zero4 = {0.f, 0.f, 0.f, 0.f};
#pragma unroll
    for (int m = 0; m < 4; ++m)
#pragma unroll
        for (int n = 0; n < 4; ++n) acc[m][n] = zero4;
    for (int kc = 0; kc < 6; ++kc) {
#pragma unroll
        for (int i = 0; i < 4; ++i) {
            int rr = w * 32 + i * 8 + (lane >> 3);
            int gg = (lane & 7) ^ (rr & 7);
            gload16(mq_b + (size_t)(r0 + rr) * DK_ + kc * 64 + gg * 8,
                    &At[(w * 32 + i * 8) * 64]);
            gload16(WmT + (size_t)(c0 + rr) * DK_ + kc * 64 + gg * 8,
                    &Bt[(w * 32 + i * 8) * 64]);
        }
        __syncthreads();
#pragma unroll
        for (int s = 0; s < 2; ++s) {
            bf16x8 af[4], bb[4];
#pragma unroll
            for (int m = 0; m < 4; ++m) {
                int rl = wr * 64 + m * 16 + lrow;
                af[m] = *reinterpret_cast<const bf16x8*>(
                    &At[rl * 64 + (((s * 4 + lkg) ^ (rl & 7)) * 8)]);
            }
#pragma unroll
            for (int n = 0; n < 4; ++n) {
                int cl = wc * 64 + n * 16 + lrow;
                bb[n] = *reinterpret_cast<const bf16x8*>(
                    &Bt[cl * 64 + (((s * 4 + lkg) ^ (cl & 7)) * 8)]);
            }
#pragma unroll
            for (int m = 0; m < 4; ++m)
#pragma unroll
                for (int n = 0; n < 4; ++n)
                    acc[m][n] = __builtin_amdgcn_mfma_f32_16x16x32_bf16(
                        af[m], bb[n], acc[m][n], 0, 0, 0);
        }
        __syncthreads();
    }
#pragma unroll
    for (int m = 0; m < 4; ++m)
#pragma unroll
        for (int n = 0; n < 4; ++n) {
            int colg = c0 + wc * 64 + n * 16 + lrow;
#pragma unroll
            for (int r = 0; r < 4; ++r) {
                int rowl = wr * 64 + m * 16 + lkg * 4 + r;
                size_t off = (size_t)(r0 + rowl) * D_ + colg;
                out[off] = acc[m][n][r] * dinv[rowl] + hs[off];
            }
        }
}

// ---------------- k_mk: per mem-token row: mk, denom2, nic, mb; also mem_b bf16
__global__ __launch_bounds__(256) void k_mk(const float* __restrict__ out,
                                            const float* __restrict__ Wmk,
                                            const float* __restrict__ Wmb_w,
                                            const float* __restrict__ Wmb_b,
                                            const float* __restrict__ z,
                                            float* __restrict__ mk_g,
                                            u16* __restrict__ mk_b,
                                            u16* __restrict__ mem_b,
                                            float* __restrict__ scal) {
    __shared__ float memRow[D_];
    __shared__ float qpart[4][64];
    __shared__ float xv[128];
    __shared__ float mks[DK_];
    __shared__ float red[256];
    const int j = blockIdx.x;
    const int tid = threadIdx.x;
    const float* mem = out + (size_t)(S_ - NMEM_ + j) * D_;
    const float4* mem4 = reinterpret_cast<const float4*>(mem);
    float4* mr4 = reinterpret_cast<float4*>(memRow);
#pragma unroll
    for (int i4 = tid; i4 < 512; i4 += 256) {
        float4 v = mem4[i4];
        mr4[i4] = v;
        ushort4 p;
        p.x = f2bf(v.x); p.y = f2bf(v.y); p.z = f2bf(v.z); p.w = f2bf(v.w);
        *reinterpret_cast<ushort4*>(&mem_b[(size_t)j * D_ + i4 * 4]) = p;
    }
    __syncthreads();
    {
        int c = tid & 63, seg = tid >> 6;
        const float4* wrow = reinterpret_cast<const float4*>(Wmk + (size_t)c * D_);
        float p = 0.f;
#pragma unroll 4
        for (int k4 = seg * 128; k4 < seg * 128 + 128; ++k4) {
            float4 a = mr4[k4], b = wrow[k4];
            p += a.x * b.x + a.y * b.y + a.z * b.z + a.w * b.w;
        }
        qpart[seg][c] = p;
    }
    __syncthreads();
    if (tid < 64) {
        float q = qpart[0][tid] + qpart[1][tid] + qpart[2][tid] + qpart[3][tid];
        xv[tid] = fmaxf(q, 0.f);
        xv[tid + 64] = fmaxf(-q, 0.f);
    }
    __syncthreads();
    for (int m = tid; m < DK_; m += 256) {
        int i = m & 127, g = m >> 7;
        float v = xv[i] * xv[(i - g - 1) & 127];
        mks[m] = v;
        mk_g[(size_t)j * DK_ + m] = v;
        mk_b[(size_t)j * DK_ + m] = f2bf(v);
    }
    __syncthreads();
    float pd = 0.f, ps = 0.f;
    for (int m = tid; m < DK_; m += 256) { float v = mks[m]; pd += v * z[m]; ps += v * v; }
    red[tid] = pd; __syncthreads();
    for (int s = 128; s > 0; s >>= 1) { if (tid < s) red[tid] += red[tid + s]; __syncthreads(); }
    float denom2 = red[0] + EPS_;
    __syncthreads();
    red[tid] = ps; __syncthreads();
    for (int s = 128; s > 0; s >>= 1) { if (tid < s) red[tid] += red[tid + s]; __syncthreads(); }
    float mksq = red[0];
    __syncthreads();
    float pb = 0.f;
    {
        const float4* wb4 = reinterpret_cast<const float4*>(Wmb_w);
#pragma unroll
        for (int k4 = tid; k4 < 512; k4 += 256) {
            float4 a = mr4[k4], b = wb4[k4];
            pb += a.x * b.x + a.y * b.y + a.z * b.z + a.w * b.w;
        }
    }
    red[tid] = pb; __syncthreads();
    for (int s = 128; s > 0; s >>= 1) { if (tid < s) red[tid] += red[tid + s]; __syncthreads(); }
    if (tid == 0) {
        float bsum = red[0] + Wmb_b[0];
        float mb = 1.f / (1.f + expf(-bsum));
        float nic = 1.f - denom2 / (mksq + EPS_);
        nic = fminf(fmaxf(nic, 0.f), 1.f);
        scal[j * 4 + 0] = denom2;
        scal[j * 4 + 1] = nic;
        scal[j * 4 + 2] = mb;
        scal[j * 4 + 3] = mksq;
    }
}

// ---------------- k_mv (MFMA): mvb = (mem@Wmv^T - (mk@W_mem)/denom2)*mb
// BM=128, BN=64 -> grid 32
__global__ __launch_bounds__(256) void k_mv(const u16* __restrict__ mem_b,
                                            const u16* __restrict__ Wmv_b,
                                            const u16* __restrict__ mk_b,
                                            const u16* __restrict__ WmT,
                                            const float* __restrict__ scal,
                                            float* __restrict__ mvb) {
    __shared__ u16 At[128 * 64];
    __shared__ u16 Bt[64 * 64];
    __shared__ float inv2[128];
    __shared__ float mbl[128];
    const int c0 = blockIdx.x * 64;
    const int tid = threadIdx.x;
    const int lane = tid & 63, w = tid >> 6;
    const int lrow = lane & 15, lkg = lane >> 4;
    const int wr = w >> 1, wc = w & 1;
    if (tid < 128) {
        inv2[tid] = 1.f / scal[tid * 4 + 0];
        mbl[tid] = scal[tid * 4 + 2];
    }
    f32x4 acc1[4][2], acc2[4][2];
    const f32x4 zero4 = {0.f, 0.f, 0.f, 0.f};
#pragma unroll
    for (int m = 0; m < 4; ++m)
#pragma unroll
        for (int n = 0; n < 2; ++n) { acc1[m][n] = zero4; acc2[m][n] = zero4; }
    for (int kc = 0; kc < D_ / 64; ++kc) {
#pragma unroll
        for (int i = 0; i < 4; ++i) {
            int rr = w * 32 + i * 8 + (lane >> 3);
            int gg = (lane & 7) ^ (rr & 7);
            gload16(mem_b + (size_t)rr * D_ + kc * 64 + gg * 8,
                    &At[(w * 32 + i * 8) * 64]);
        }
#pragma unroll
        for (int i = 0; i < 2; ++i) {
            int cc = w * 16 + i * 8 + (lane >> 3);
            int gg = (lane & 7) ^ (cc & 7);
            gload16(Wmv_b + (size_t)(c0 + cc) * D_ + kc * 64 + gg * 8,
                    &Bt[(w * 16 + i * 8) * 64]);
        }
        __syncthreads();
#pragma unroll
        for (int s = 0; s < 2; ++s) {
            bf16x8 af[4], bb[2];
#pragma unroll
            for (int m = 0; m < 4; ++m) {
                int rl = wr * 64 + m * 16 + lrow;
                af[m] = *reinterpret_cast<const bf16x8*>(
                    &At[rl * 64 + (((s * 4 + lkg) ^ (rl & 7)) * 8)]);
            }
#pragma unroll
            for (int n = 0; n < 2; ++n) {
                int cl = wc * 32 + n * 16 + lrow;
                bb[n] = *reinterpret_cast<const bf16x8*>(
                    &Bt[cl * 64 + (((s * 4 + lkg) ^ (cl & 7)) * 8)]);
            }
#pragma unroll
            for (int m = 0; m < 4; ++m)
#pragma unroll
                for (int n = 0; n < 2; ++n)
                    acc1[m][n] = __builtin_amdgcn_mfma_f32_16x16x32_bf16(
                        af[m], bb[n], acc1[m][n], 0, 0, 0);
        }
        __syncthreads();
    }
    for (int kc = 0; kc < 6; ++kc) {
#pragma unroll
        for (int i = 0; i < 4; ++i) {
            int rr = w * 32 + i * 8 + (lane >> 3);
            int gg = (lane & 7) ^ (rr & 7);
            gload16(mk_b + (size_t)rr * DK_ + kc * 64 + gg * 8,
                    &At[(w * 32 + i * 8) * 64]);
        }
#pragma unroll
        for (int i = 0; i < 2; ++i) {
            int cc = w * 16 + i * 8 + (lane >> 3);
            int gg = (lane & 7) ^ (cc & 7);
            gload16(WmT + (size_t)(c0 + cc) * DK_ + kc * 64 + gg * 8,
                    &Bt[(w * 16 + i * 8) * 64]);
        }
        __syncthreads();
#pragma unroll
        for (int s = 0; s < 2; ++s) {
            bf16x8 af[4], bb[2];
#pragma unroll
            for (int m = 0; m < 4; ++m) {
                int rl = wr * 64 + m * 16 + lrow;
                af[m] = *reinterpret_cast<const bf16x8*>(
                    &At[rl * 64 + (((s * 4 + lkg) ^ (rl & 7)) * 8)]);
            }
#pragma unroll
            for (int n = 0; n < 2; ++n) {
                int cl = wc * 32 + n * 16 + lrow;
                bb[n] = *reinterpret_cast<const bf16x8*>(
                    &Bt[cl * 64 + (((s * 4 + lkg) ^ (cl & 7)) * 8)]);
            }
#pragma unroll
            for (int m = 0; m < 4; ++m)
#pragma unroll
                for (int n = 0; n < 2; ++n)
                    acc2[m][n] = __builtin_amdgcn_mfma_f32_16x16x32_bf16(
                        af[m], bb[n], acc2[m][n], 0, 0, 0);
        }
        __syncthreads();
    }
#pragma unroll
    for (int m = 0; m < 4; ++m)
#pragma unroll
        for (int n = 0; n < 2; ++n) {
            int colg = c0 + wc * 32 + n * 16 + lrow;
#pragma unroll
            for (int r = 0; r < 4; ++r) {
                int j = wr * 64 + m * 16 + lkg * 4 + r;
                mvb[(size_t)j * D_ + colg] =
                    (acc1[m][n][r] - acc2[m][n][r] * inv2[j]) * mbl[j];
            }
        }
}

// ---------------- k_wmem: W_mem_new = W_mem + mk^T @ mvb (float4) ; y==48 z_new
__global__ __launch_bounds__(256) void k_wmem(const float* __restrict__ Wmem,
                                              const float* __restrict__ mk_g,
                                              const float* __restrict__ mvb,
                                              const float* __restrict__ scal,
                                              const float* __restrict__ z,
                                              float* __restrict__ wout,
                                              float* __restrict__ zout) {
    const int tid = threadIdx.x;
    if (blockIdx.y == 48) {
        if (blockIdx.x == 0) {
            for (int t = tid; t < DK_; t += 256) {
                float acc = z[t];
                for (int j = 0; j < NMEM_; ++j)
                    acc += scal[j * 4 + 1] * mk_g[(size_t)j * DK_ + t];
                zout[t] = acc;
            }
        }
        return;
    }
    const int c0 = blockIdx.x * 256;
    const int k0 = blockIdx.y * 8;
    const int tk = tid >> 5, tt = tid & 31;
    const float4* mvb4 = reinterpret_cast<const float4*>(mvb);
    f32x4 acc[2] = {{0.f, 0.f, 0.f, 0.f}, {0.f, 0.f, 0.f, 0.f}};
#pragma unroll 4
    for (int j = 0; j < NMEM_; ++j) {
        float a = mk_g[(size_t)j * DK_ + k0 + tk];
#pragma unroll
        for (int i = 0; i < 2; ++i) {
            float4 v = mvb4[((size_t)j * D_ + c0 + tt * 4 + 128 * i) >> 2];
            acc[i][0] += a * v.x; acc[i][1] += a * v.y;
            acc[i][2] += a * v.z; acc[i][3] += a * v.w;
        }
    }
#pragma unroll
    for (int i = 0; i < 2; ++i) {
        size_t off = (size_t)(k0 + tk) * D_ + c0 + tt * 4 + 128 * i;
        float4 wv = *reinterpret_cast<const float4*>(&Wmem[off]);
        float4 o;
        o.x = wv.x + acc[i][0]; o.y = wv.y + acc[i][1];
        o.z = wv.z + acc[i][2]; o.w = wv.w + acc[i][3];
        *reinterpret_cast<float4*>(&wout[off]) = o;
    }
}

extern "C" void kernel_launch(void* const* d_in, const int* in_sizes, int n_in,
                              void* d_out, int out_size, void* d_ws, size_t ws_size,
                              hipStream_t stream) {
    const float* hs   = (const float*)d_in[0];
    const float* Wmq  = (const float*)d_in[1];
    const float* Wmk  = (const float*)d_in[2];
    const float* Wmv  = (const float*)d_in[3];
    const float* Wmbw = (const float*)d_in[4];
    const float* Wmbb = (const float*)d_in[5];
    const float* Wmem = (const float*)d_in[6];
    const float* z    = (const float*)d_in[7];
    float* out  = (float*)d_out;
    float* wout = out + (size_t)S_ * D_;
    float* zout = wout + (size_t)DK_ * D_;

    float* ws = (float*)d_ws;
    float* denomv = ws;                              // 16384
    float* mk_g   = denomv + S_;                     // 128*384
    float* scal   = mk_g + (size_t)NMEM_ * DK_;      // 512
    float* mvb    = scal + NMEM_ * 4;                // 128*2048
    u16* mq_b  = (u16*)(mvb + (size_t)NMEM_ * D_);   // 16384*384 bf16
    u16* WmT   = mq_b + (size_t)S_ * DK_;            // 2048*384 bf16
    u16* Wmq_b = WmT + (size_t)D_ * DK_;             // 64*2048 bf16
    u16* Wmv_b = Wmq_b + (size_t)DM_ * D_;           // 2048*2048 bf16
    u16* mem_b = Wmv_b + (size_t)D_ * D_;            // 128*2048 bf16
    u16* mk_b  = mem_b + (size_t)NMEM_ * D_;         // 128*384 bf16

    k_prep<<<dim3(4992), 256, 0, stream>>>(Wmq, Wmv, Wmem, Wmq_b, Wmv_b, WmT);
    k_qdp<<<dim3(S_ / 32), 256, 0, stream>>>(hs, Wmq_b, z, mq_b, denomv);
    k_main<<<dim3((S_ / 128) * (D_ / 128)), 256, 0, stream>>>(hs, mq_b, WmT, denomv, out);
    k_mk<<<dim3(NMEM_), 256, 0, stream>>>(out, Wmk, Wmbw, Wmbb, z, mk_g, mk_b, mem_b, scal);
    k_mv<<<dim3(D_ / 64), 256, 0, stream>>>(mem_b, Wmv_b, mk_b, WmT, scal, mvb);
    k_wmem<<<dim3(D_ / 256, DK_ / 8 + 1), 256, 0, stream>>>(Wmem, mk_g, mvb, scal, z, wout, zout);
}